// Round 4
// baseline (672.260 us; speedup 1.0000x reference)
//
#include <hip/hip_runtime.h>

constexpr int Ld = 4096;
constexpr int Dd = 128;
constexpr int BQ = 128;
constexpr int BK = 64;
constexpr int WSZ = 2048;
constexpr int NSINK = 4;
// 1/sqrt(128) * log2(e)  (exp2-domain softmax; common factor cancels exactly)
constexpr float QSCALE = 0.08838834764831845f * 1.4426950408889634f;

typedef short bf16x8 __attribute__((ext_vector_type(8)));
typedef float f32x4 __attribute__((ext_vector_type(4)));

#if defined(__has_builtin)
#if __has_builtin(__builtin_amdgcn_exp2f)
#define EXP2(x) __builtin_amdgcn_exp2f(x)
#endif
#endif
#ifndef EXP2
#define EXP2(x) exp2f(x)
#endif

// gfx950 packed fp32->bf16 (RNE): dst[15:0]=bf16(src0), dst[31:16]=bf16(src1)
__device__ __forceinline__ unsigned pkbf(float hi, float lo) {
    unsigned r;
    asm("v_cvt_pk_bf16_f32 %0, %1, %2" : "=v"(r) : "v"(lo), "v"(hi));
    return r;
}

// --- swizzled LDS offsets (ushort units) ---
__device__ __forceinline__ int rd_off(int row, int d) {    // [rows][128]
    return row * 128 + ((((d >> 3) ^ row) & 15) << 3) + (d & 7);
}
__device__ __forceinline__ int vt_off(int drow, int key) { // [128][64] (V^T)
    return drow * 64 + ((((key >> 3) ^ drow) & 7) << 3) + (key & 7);
}
__device__ __forceinline__ int p_off(int row, int key) {   // [16][64], b64-granular
    return row * 64 + ((((key >> 2) ^ ((row & 7) << 1)) & 15) << 2) + (key & 3);
}

// async global->LDS DMA, 16B per lane; lds must be wave-uniform base
typedef const __attribute__((address_space(1))) void* gas_p;
typedef __attribute__((address_space(3))) void* las_p;
__device__ __forceinline__ void dma16(const void* g, void* l) {
    __builtin_amdgcn_global_load_lds((gas_p)g, (las_p)l, 16, 0, 0);
}

// ============ pre-pass: build bf16 LDS-image tiles for K and V^T ============
// Wk[bh][c] : 8192 ushorts, image of rd_off-swizzled K chunk [64 keys][128 d]
// Wv[bh][c] : 8192 ushorts, image of vt_off-swizzled V^T chunk [128 d][64 keys]
__global__ __launch_bounds__(256, 4)
void prep(const float* __restrict__ Kg, const float* __restrict__ Vg,
          unsigned short* __restrict__ Wk, unsigned short* __restrict__ Wv) {
    __shared__ __align__(16) unsigned short Vst[8192];
    const int c = blockIdx.x, bh = blockIdx.y, tid = threadIdx.x;
    const size_t src = ((size_t)bh * Ld + c * 64) * Dd;
    unsigned short* kimg = Wk + (((size_t)bh * 64 + c) << 13);
    unsigned short* vimg = Wv + (((size_t)bh * 64 + c) << 13);

    // K image: img_u4[idx] covers ushorts [idx*8, idx*8+8): row=idx>>4,
    // d0=(((idx&15)^row)&15)*8 -> linear coalesced writes.
    #pragma unroll
    for (int i = 0; i < 4; ++i) {
        int idx = tid + i * 256;
        int row = idx >> 4;
        int d0  = (((idx & 15) ^ row) & 15) << 3;
        const float* kp = Kg + src + (size_t)row * Dd + d0;
        float4 a = *(const float4*)kp;
        float4 b = *(const float4*)(kp + 4);
        *(uint4*)&kimg[idx * 8] =
            make_uint4(pkbf(a.y, a.x), pkbf(a.w, a.z),
                       pkbf(b.y, b.x), pkbf(b.w, b.z));
    }
    // V^T: stage transposed+swizzled into LDS, then dump linearly.
    {
        int d  = tid & 127;
        int kh = tid >> 7;
        const float* vp = Vg + src + (size_t)(kh * 32) * Dd + d;
        #pragma unroll
        for (int m2 = 0; m2 < 4; ++m2) {
            float e0 = vp[(m2 * 8 + 0) * Dd], e1 = vp[(m2 * 8 + 1) * Dd];
            float e2 = vp[(m2 * 8 + 2) * Dd], e3 = vp[(m2 * 8 + 3) * Dd];
            float e4 = vp[(m2 * 8 + 4) * Dd], e5 = vp[(m2 * 8 + 5) * Dd];
            float e6 = vp[(m2 * 8 + 6) * Dd], e7 = vp[(m2 * 8 + 7) * Dd];
            *(uint4*)&Vst[vt_off(d, kh * 32 + m2 * 8)] =
                make_uint4(pkbf(e1, e0), pkbf(e3, e2),
                           pkbf(e5, e4), pkbf(e7, e6));
        }
    }
    __syncthreads();
    #pragma unroll
    for (int i = 0; i < 4; ++i) {
        int idx = tid + i * 256;
        *(uint4*)&vimg[idx * 8] = *(const uint4*)&Vst[idx * 8];
    }
}

// ============ main kernel: DMA-staged flash attention ============
__global__ __launch_bounds__(256, 3)
void swa_fwd(const float* __restrict__ Qg,
             const unsigned short* __restrict__ Wk,
             const unsigned short* __restrict__ Wv,
             float* __restrict__ Og) {
    // separate objects -> clean alias analysis (no spurious vmcnt waits)
    __shared__ __align__(16) unsigned short Ks[8192];   // K chunk image
    __shared__ __align__(16) unsigned short Vts[8192];  // V^T chunk image
    __shared__ __align__(16) unsigned short Ps[8192];   // per-wave P regions

    const int tid  = threadIdx.x;
    const int w    = tid >> 6;
    const int lane = tid & 63;
    const int ml   = lane & 15;
    const int quad = lane >> 4;

    const int qtile = (int)(gridDim.x - 1u - blockIdx.x); // longest first
    const int q0 = qtile * BQ;
    const int bh = blockIdx.y;

    // ---- Q B-fragments straight from global (scaled fp32 -> bf16) ----
    bf16x8 qf[2][4];
    #pragma unroll
    for (int g = 0; g < 2; ++g) {
        const float* qp = Qg + ((size_t)bh * Ld + q0 + w * 32 + g * 16 + ml) * Dd;
        #pragma unroll
        for (int k0 = 0; k0 < 4; ++k0) {
            const float* p = qp + k0 * 32 + quad * 8;
            float4 a = *(const float4*)p;
            float4 b = *(const float4*)(p + 4);
            uint4 u = make_uint4(
                pkbf(a.y * QSCALE, a.x * QSCALE), pkbf(a.w * QSCALE, a.z * QSCALE),
                pkbf(b.y * QSCALE, b.x * QSCALE), pkbf(b.w * QSCALE, b.z * QSCALE));
            qf[g][k0] = *(bf16x8*)&u;
        }
    }

    float m_i[2] = {-3e38f, -3e38f};
    float l_i[2] = {0.f, 0.f};
    f32x4 o_acc[2][8];
    #pragma unroll
    for (int g = 0; g < 2; ++g)
        #pragma unroll
        for (int dt = 0; dt < 8; ++dt)
            o_acc[g][dt] = (f32x4){0.f, 0.f, 0.f, 0.f};

    const int kmin = (q0 - (WSZ - 1)) > 0 ? (q0 - (WSZ - 1)) : 0;
    const int kb_first = (kmin / BK) * BK;
    const bool sink_extra = (kb_first > 0);
    const int nch = (q0 + BQ - kb_first) / BK + (sink_extra ? 1 : 0);
    auto kb_of = [&](int ci) {
        return sink_extra ? (ci == 0 ? 0 : kb_first + (ci - 1) * BK)
                          : kb_first + ci * BK;
    };

    const unsigned short* kim0 = Wk + ((size_t)bh << 19); // bh*64*8192
    const unsigned short* vim0 = Wv + ((size_t)bh << 19);

    // ---- prime chunk 0: K via DMA, V via register loads ----
    uint4 vr[4];
    {
        const int c0 = kb_of(0) >> 6;
        const unsigned short* kg = kim0 + ((size_t)c0 << 13) + w * 2048 + lane * 8;
        #pragma unroll
        for (int i = 0; i < 4; ++i)
            dma16(kg + i * 512, &Ks[w * 2048 + i * 512]);
        const uint4* vg = (const uint4*)(vim0 + ((size_t)c0 << 13));
        #pragma unroll
        for (int i = 0; i < 4; ++i) vr[i] = vg[tid + i * 256];
    }

    const int qrow0 = q0 + w * 32 + ml;
    unsigned short* Pw = Ps + w * 2048;

    for (int ci = 0; ci < nch; ++ci) {
        const int kb = kb_of(ci);

        __syncthreads(); // top: drains K-DMA(ci)+V-loads(ci); prev readers done

        // ---- V^T image: registers -> LDS, linear b128 (no conversion) ----
        #pragma unroll
        for (int i = 0; i < 4; ++i)
            *(uint4*)&Vts[(tid + i * 256) * 8] = vr[i];

        // ---- S^T = K . Q^T : Ks ready since top barrier ----
        f32x4 s[2][4];
        #pragma unroll
        for (int g = 0; g < 2; ++g)
            #pragma unroll
            for (int t = 0; t < 4; ++t)
                s[g][t] = (f32x4){0.f, 0.f, 0.f, 0.f};
        #pragma unroll
        for (int k0 = 0; k0 < 4; ++k0) {
            bf16x8 ka[4];
            #pragma unroll
            for (int t = 0; t < 4; ++t)
                ka[t] = *(const bf16x8*)&Ks[rd_off(t * 16 + ml, k0 * 32 + quad * 8)];
            #pragma unroll
            for (int t = 0; t < 4; ++t) {
                s[0][t] = __builtin_amdgcn_mfma_f32_16x16x32_bf16(ka[t], qf[0][k0], s[0][t], 0, 0, 0);
                s[1][t] = __builtin_amdgcn_mfma_f32_16x16x32_bf16(ka[t], qf[1][k0], s[1][t], 0, 0, 0);
            }
        }

        __syncthreads(); // mid: all QK reads done (Ks free); Vt writes visible

        // ---- issue next chunk's staging; in flight through softmax+PV ----
        if (ci + 1 < nch) {
            const int c2 = kb_of(ci + 1) >> 6;
            const unsigned short* kg = kim0 + ((size_t)c2 << 13) + w * 2048 + lane * 8;
            #pragma unroll
            for (int i = 0; i < 4; ++i)
                dma16(kg + i * 512, &Ks[w * 2048 + i * 512]);
            const uint4* vg = (const uint4*)(vim0 + ((size_t)c2 << 13));
            #pragma unroll
            for (int i = 0; i < 4; ++i) vr[i] = vg[tid + i * 256];
        }

        // fully-in-window chunk? (block-uniform; skips all masking)
        const bool full = (kb + (BK - 1) <= q0) && (kb + (WSZ - BQ) >= q0 - 1);

        #pragma unroll
        for (int g = 0; g < 2; ++g) {
            const int q = qrow0 + g * 16;
            if (!full) {
                #pragma unroll
                for (int t = 0; t < 4; ++t)
                    #pragma unroll
                    for (int r = 0; r < 4; ++r) {
                        int k = kb + t * 16 + quad * 4 + r;
                        bool ok = (k <= q) && ((k + (WSZ - 1) >= q) || (k < NSINK));
                        s[g][t][r] = ok ? s[g][t][r] : -3e38f;
                    }
            }
            // per-lane (q=ml) softmax over own 16 keys, reduce across 4 quads
            float mx = s[g][0][0];
            #pragma unroll
            for (int t = 0; t < 4; ++t)
                #pragma unroll
                for (int r = 0; r < 4; ++r) mx = fmaxf(mx, s[g][t][r]);
            mx = fmaxf(mx, __shfl_xor(mx, 16));
            mx = fmaxf(mx, __shfl_xor(mx, 32));
            const float mnew = fmaxf(m_i[g], mx);
            const float alpha = EXP2(m_i[g] - mnew);
            m_i[g] = mnew;
            float rs = 0.f;
            #pragma unroll
            for (int t = 0; t < 4; ++t)
                #pragma unroll
                for (int r = 0; r < 4; ++r) {
                    float p = EXP2(s[g][t][r] - mnew); // masked -> exact 0
                    s[g][t][r] = p;
                    rs += p;
                }
            rs += __shfl_xor(rs, 16);
            rs += __shfl_xor(rs, 32);
            l_i[g] = alpha * l_i[g] + rs;

            // P store: lane holds 4 consecutive keys per t -> b64 writes
            unsigned short* Pg = Pw + g * 1024;
            #pragma unroll
            for (int t = 0; t < 4; ++t)
                *(uint2*)&Pg[p_off(ml, t * 16 + quad * 4)] =
                    make_uint2(pkbf(s[g][t][1], s[g][t][0]),
                               pkbf(s[g][t][3], s[g][t][2]));
            // rescale O accumulator (alpha per-lane matches O^T q-column)
            #pragma unroll
            for (int dt = 0; dt < 8; ++dt) o_acc[g][dt] *= alpha;
        }

        // ---- O^T += V^T . P^T : 2 groups share Vt A-frags ----
        #pragma unroll
        for (int k0 = 0; k0 < 2; ++k0) {
            bf16x8 pb0 = *(const bf16x8*)&Pw[p_off(ml, k0 * 32 + quad * 8)];
            bf16x8 pb1 = *(const bf16x8*)&Pw[1024 + p_off(ml, k0 * 32 + quad * 8)];
            #pragma unroll
            for (int dt = 0; dt < 8; ++dt) {
                bf16x8 va = *(const bf16x8*)&Vts[vt_off(dt * 16 + ml, k0 * 32 + quad * 8)];
                o_acc[0][dt] = __builtin_amdgcn_mfma_f32_16x16x32_bf16(va, pb0, o_acc[0][dt], 0, 0, 0);
                o_acc[1][dt] = __builtin_amdgcn_mfma_f32_16x16x32_bf16(va, pb1, o_acc[1][dt], 0, 0, 0);
            }
        }
    }

    // ---- epilogue: O[q][d] = O^T / l, vectorized float4 stores ----
    #pragma unroll
    for (int g = 0; g < 2; ++g) {
        const float inv = 1.f / l_i[g];
        float* op = Og + ((size_t)bh * Ld + (qrow0 + g * 16)) * Dd;
        #pragma unroll
        for (int dt = 0; dt < 8; ++dt) {
            float4 o;
            o.x = o_acc[g][dt][0] * inv;
            o.y = o_acc[g][dt][1] * inv;
            o.z = o_acc[g][dt][2] * inv;
            o.w = o_acc[g][dt][3] * inv;
            *(float4*)(op + dt * 16 + quad * 4) = o;
        }
    }
}

// ============ fallback (R3, proven) for small ws_size ============
__global__ __launch_bounds__(256, 2)
void swa_fwd_fb(const float* __restrict__ Qg, const float* __restrict__ Kg,
                const float* __restrict__ Vg, float* __restrict__ Og) {
    __shared__ __align__(16) unsigned short smem[24576];
    unsigned short* Ks  = smem;
    unsigned short* Vts = smem + 8192;
    unsigned short* Ps  = smem + 16384;
    unsigned short* Qst = smem;

    const int tid  = threadIdx.x;
    const int w    = tid >> 6;
    const int lane = tid & 63;
    const int ml   = lane & 15;
    const int quad = lane >> 4;

    const int qtile = (int)(gridDim.x - 1u - blockIdx.x);
    const int q0 = qtile * BQ;
    const int bh = blockIdx.y;

    const size_t baseQ  = ((size_t)bh * Ld + q0) * Dd;
    const size_t baseKV = (size_t)bh * Ld * Dd;

    #pragma unroll
    for (int i = 0; i < 16; ++i) {
        int idx = tid + i * 256;
        int row = idx >> 5;
        int d0  = (idx & 31) << 2;
        float4 v = *(const float4*)(Qg + baseQ + (size_t)row * Dd + d0);
        *(uint2*)&Qst[rd_off(row, d0)] =
            make_uint2(pkbf(v.y * QSCALE, v.x * QSCALE),
                       pkbf(v.w * QSCALE, v.z * QSCALE));
    }
    __syncthreads();

    bf16x8 qf[2][4];
    #pragma unroll
    for (int g = 0; g < 2; ++g)
        #pragma unroll
        for (int k0 = 0; k0 < 4; ++k0)
            qf[g][k0] = *(const bf16x8*)&Qst[rd_off(w * 32 + g * 16 + ml,
                                                    k0 * 32 + quad * 8)];

    float m_i[2] = {-3e38f, -3e38f};
    float l_i[2] = {0.f, 0.f};
    f32x4 o_acc[2][8];
    #pragma unroll
    for (int g = 0; g < 2; ++g)
        #pragma unroll
        for (int dt = 0; dt < 8; ++dt)
            o_acc[g][dt] = (f32x4){0.f, 0.f, 0.f, 0.f};

    const int kmin = (q0 - (WSZ - 1)) > 0 ? (q0 - (WSZ - 1)) : 0;
    const int kb_first = (kmin / BK) * BK;
    const bool sink_extra = (kb_first > 0);
    const int nch = (q0 + BQ - kb_first) / BK + (sink_extra ? 1 : 0);

    const int qrow0 = q0 + w * 32 + ml;
    unsigned short* Pw = Ps + w * 2048;

    float4 kreg[8];
    float  vreg[32];
    const int kr0 = tid >> 5;
    const int kd0 = (tid & 31) << 2;
    const int vd  = tid & 127;
    const int vkh = tid >> 7;

    auto kvload = [&](int kb) {
        const float* kp = Kg + baseKV + (size_t)(kb + kr0) * Dd + kd0;
        #pragma unroll
        for (int i = 0; i < 8; ++i)
            kreg[i] = *(const float4*)(kp + (size_t)i * 8 * Dd);
        const float* vp = Vg + baseKV + (size_t)(kb + vkh * 32) * Dd + vd;
        #pragma unroll
        for (int j = 0; j < 32; ++j)
            vreg[j] = vp[(size_t)j * Dd];
    };
    auto kb_of = [&](int ci) {
        return sink_extra ? (ci == 0 ? 0 : kb_first + (ci - 1) * BK)
                          : kb_first + ci * BK;
    };

    kvload(kb_of(0));

    for (int ci = 0; ci < nch; ++ci) {
        const int kb = kb_of(ci);
        __syncthreads();
        #pragma unroll
        for (int i = 0; i < 8; ++i)
            *(uint2*)&Ks[rd_off(kr0 + i * 8, kd0)] =
                make_uint2(pkbf(kreg[i].y, kreg[i].x),
                           pkbf(kreg[i].w, kreg[i].z));
        #pragma unroll
        for (int m2 = 0; m2 < 4; ++m2) {
            *(uint4*)&Vts[vt_off(vd, vkh * 32 + m2 * 8)] =
                make_uint4(pkbf(vreg[m2 * 8 + 1], vreg[m2 * 8 + 0]),
                           pkbf(vreg[m2 * 8 + 3], vreg[m2 * 8 + 2]),
                           pkbf(vreg[m2 * 8 + 5], vreg[m2 * 8 + 4]),
                           pkbf(vreg[m2 * 8 + 7], vreg[m2 * 8 + 6]));
        }
        __syncthreads();
        if (ci + 1 < nch) kvload(kb_of(ci + 1));

        f32x4 s[2][4];
        #pragma unroll
        for (int g = 0; g < 2; ++g)
            #pragma unroll
            for (int t = 0; t < 4; ++t)
                s[g][t] = (f32x4){0.f, 0.f, 0.f, 0.f};
        #pragma unroll
        for (int k0 = 0; k0 < 4; ++k0) {
            bf16x8 ka[4];
            #pragma unroll
            for (int t = 0; t < 4; ++t)
                ka[t] = *(const bf16x8*)&Ks[rd_off(t * 16 + ml, k0 * 32 + quad * 8)];
            #pragma unroll
            for (int t = 0; t < 4; ++t) {
                s[0][t] = __builtin_amdgcn_mfma_f32_16x16x32_bf16(ka[t], qf[0][k0], s[0][t], 0, 0, 0);
                s[1][t] = __builtin_amdgcn_mfma_f32_16x16x32_bf16(ka[t], qf[1][k0], s[1][t], 0, 0, 0);
            }
        }

        const bool full = (kb + (BK - 1) <= q0) && (kb + (WSZ - BQ) >= q0 - 1);

        #pragma unroll
        for (int g = 0; g < 2; ++g) {
            const int q = qrow0 + g * 16;
            if (!full) {
                #pragma unroll
                for (int t = 0; t < 4; ++t)
                    #pragma unroll
                    for (int r = 0; r < 4; ++r) {
                        int k = kb + t * 16 + quad * 4 + r;
                        bool ok = (k <= q) && ((k + (WSZ - 1) >= q) || (k < NSINK));
                        s[g][t][r] = ok ? s[g][t][r] : -3e38f;
                    }
            }
            float mx = s[g][0][0];
            #pragma unroll
            for (int t = 0; t < 4; ++t)
                #pragma unroll
                for (int r = 0; r < 4; ++r) mx = fmaxf(mx, s[g][t][r]);
            mx = fmaxf(mx, __shfl_xor(mx, 16));
            mx = fmaxf(mx, __shfl_xor(mx, 32));
            const float mnew = fmaxf(m_i[g], mx);
            const float alpha = EXP2(m_i[g] - mnew);
            m_i[g] = mnew;
            float rs = 0.f;
            #pragma unroll
            for (int t = 0; t < 4; ++t)
                #pragma unroll
                for (int r = 0; r < 4; ++r) {
                    float p = EXP2(s[g][t][r] - mnew);
                    s[g][t][r] = p;
                    rs += p;
                }
            rs += __shfl_xor(rs, 16);
            rs += __shfl_xor(rs, 32);
            l_i[g] = alpha * l_i[g] + rs;

            unsigned short* Pg = Pw + g * 1024;
            #pragma unroll
            for (int t = 0; t < 4; ++t)
                *(uint2*)&Pg[p_off(ml, t * 16 + quad * 4)] =
                    make_uint2(pkbf(s[g][t][1], s[g][t][0]),
                               pkbf(s[g][t][3], s[g][t][2]));
            #pragma unroll
            for (int dt = 0; dt < 8; ++dt) o_acc[g][dt] *= alpha;
        }

        #pragma unroll
        for (int k0 = 0; k0 < 2; ++k0) {
            bf16x8 pb0 = *(const bf16x8*)&Pw[p_off(ml, k0 * 32 + quad * 8)];
            bf16x8 pb1 = *(const bf16x8*)&Pw[1024 + p_off(ml, k0 * 32 + quad * 8)];
            #pragma unroll
            for (int dt = 0; dt < 8; ++dt) {
                bf16x8 va = *(const bf16x8*)&Vts[vt_off(dt * 16 + ml, k0 * 32 + quad * 8)];
                o_acc[0][dt] = __builtin_amdgcn_mfma_f32_16x16x32_bf16(va, pb0, o_acc[0][dt], 0, 0, 0);
                o_acc[1][dt] = __builtin_amdgcn_mfma_f32_16x16x32_bf16(va, pb1, o_acc[1][dt], 0, 0, 0);
            }
        }
    }

    #pragma unroll
    for (int g = 0; g < 2; ++g) {
        const float inv = 1.f / l_i[g];
        float* op = Og + ((size_t)bh * Ld + (qrow0 + g * 16)) * Dd;
        #pragma unroll
        for (int dt = 0; dt < 8; ++dt) {
            float4 o;
            o.x = o_acc[g][dt][0] * inv;
            o.y = o_acc[g][dt][1] * inv;
            o.z = o_acc[g][dt][2] * inv;
            o.w = o_acc[g][dt][3] * inv;
            *(float4*)(op + dt * 16 + quad * 4) = o;
        }
    }
}

extern "C" void kernel_launch(void* const* d_in, const int* in_sizes, int n_in,
                              void* d_out, int out_size, void* d_ws, size_t ws_size,
                              hipStream_t stream) {
    const float* q = (const float*)d_in[0];
    const float* k = (const float*)d_in[1];
    const float* v = (const float*)d_in[2];
    float* o = (float*)d_out;
    const int bhn = in_sizes[0] / (Ld * Dd); // B*H = 32
    const size_t need = (size_t)bhn * 64 * 8192 * 2 /*ushort*/ * 2 /*K,V*/;
    if (ws_size >= need) {
        unsigned short* Wk = (unsigned short*)d_ws;
        unsigned short* Wv = Wk + (size_t)bhn * 64 * 8192;
        prep<<<dim3(Ld / 64, bhn), dim3(256, 1, 1), 0, stream>>>(k, v, Wk, Wv);
        swa_fwd<<<dim3(Ld / BQ, bhn), dim3(256, 1, 1), 0, stream>>>(q, Wk, Wv, o);
    } else {
        swa_fwd_fb<<<dim3(Ld / BQ, bhn), dim3(256, 1, 1), 0, stream>>>(q, k, v, o);
    }
}